// Round 6
// baseline (19350.943 us; speedup 1.0000x reference)
//
#include <hip/hip_runtime.h>

#define NC 128
#define KTOP 64
#define SMLSIZ 25
#define EPSF 5.9604645e-8f
#define SAFMINF 1.17549435e-38f

// out-tail scratch (floats). out = 16,777,216 floats; scratch in top ~5.4MB,
// dead before proj overwrites out.
#define TBASEF 15400960
#define F_A    0         // 262144 f (raw cov sums -> cov, eig input, destroyed)
#define F_B    262144    // 262144 f (pristine cov for diag)
#define F_Q    524288    // 262144 f
#define F_Q2   786432    // 266240 f
#define F_SM   1052672   // 262144 f
#define F_VECS 1314816   // 18432 f
#define F_IWSP 1333248   // 6144 int

// ======================= f32 LAPACK helpers =======================

__device__ __forceinline__ float slapy2f(float x, float y) {
  float xa = fabsf(x), ya = fabsf(y);
  float w = fmaxf(xa, ya), z = fminf(xa, ya);
  if (z == 0.f) return w;
  float r = z / w;
  return w * sqrtf(1.f + r * r);
}

// LAPACK >=3.10 slartg convention (c >= 0, r carries sign of f)
__device__ __forceinline__ void slartgf(float f, float g, float* c, float* s, float* r) {
  if (g == 0.f) { *c = 1.f; *s = 0.f; *r = f; }
  else if (f == 0.f) { *c = 0.f; *s = (g >= 0.f) ? 1.f : -1.f; *r = fabsf(g); }
  else {
    float d_ = sqrtf(f * f + g * g);
    *c = fabsf(f) / d_;
    *r = (f >= 0.f) ? d_ : -d_;
    *s = g / (*r);
  }
}

__device__ void slaev2f(float a, float b, float c,
                        float* rt1, float* rt2, float* cs1, float* sn1) {
  float sm = a + c, df = a - c, adf = fabsf(df), tb = b + b, ab = fabsf(tb);
  float acmx, acmn;
  if (fabsf(a) > fabsf(c)) { acmx = a; acmn = c; } else { acmx = c; acmn = a; }
  float rt;
  if (adf > ab) { float t = ab / adf; rt = adf * sqrtf(1.f + t * t); }
  else if (adf < ab) { float t = adf / ab; rt = ab * sqrtf(1.f + t * t); }
  else rt = ab * sqrtf(2.f);
  int sgn1;
  if (sm < 0.f) { *rt1 = 0.5f * (sm - rt); sgn1 = -1; *rt2 = (acmx / (*rt1)) * acmn - (b / (*rt1)) * b; }
  else if (sm > 0.f) { *rt1 = 0.5f * (sm + rt); sgn1 = 1; *rt2 = (acmx / (*rt1)) * acmn - (b / (*rt1)) * b; }
  else { *rt1 = 0.5f * rt; *rt2 = -0.5f * rt; sgn1 = 1; }
  float cs; int sgn2;
  if (df >= 0.f) { cs = df + rt; sgn2 = 1; } else { cs = df - rt; sgn2 = -1; }
  float acs = fabsf(cs);
  if (acs > ab) {
    float ct = -tb / cs;
    *sn1 = 1.f / sqrtf(1.f + ct * ct);
    *cs1 = ct * (*sn1);
  } else {
    if (ab == 0.f) { *cs1 = 1.f; *sn1 = 0.f; }
    else { float tn = -cs / tb; *cs1 = 1.f / sqrtf(1.f + tn * tn); *sn1 = tn * (*cs1); }
  }
  if (sgn1 == sgn2) { float tn = *cs1; *cs1 = -(*sn1); *sn1 = tn; }
}

// Faithful serial ssteqr('I') for a block of size n (n <= 25), Z at zb (ldz).
__device__ void steqr_f32(float* d, float* e, int n, float* zb, int ldz) {
  const float eps = EPSF;
  const float eps2 = eps * eps;
  const float safmin = SAFMINF;
  for (int j = 0; j < n; j++)
    for (int i = 0; i < n; i++) zb[j * ldz + i] = (i == j) ? 1.f : 0.f;
  if (n <= 1) return;
  float cw[32], sw[32];
  int nmaxit = n * 30, jtot = 0;
  int l1 = 1;
  while (true) {
    if (l1 > n) break;
    if (l1 > 1) e[l1 - 2] = 0.f;
    int m;
    {
      int mm_;
      for (mm_ = l1; mm_ <= n - 1; mm_++) {
        float tst = fabsf(e[mm_ - 1]);
        if (tst == 0.f) break;
        if (tst <= (sqrtf(fabsf(d[mm_ - 1])) * sqrtf(fabsf(d[mm_]))) * eps) { e[mm_ - 1] = 0.f; break; }
      }
      m = mm_;
    }
    int l = l1, lsv = l, lend = m, lendsv = lend;
    l1 = m + 1;
    if (lend == l) continue;
    float anorm = 0.f;
    for (int i = l; i <= lend; i++) anorm = fmaxf(anorm, fabsf(d[i - 1]));
    for (int i = l; i <= lend - 1; i++) anorm = fmaxf(anorm, fabsf(e[i - 1]));
    if (anorm == 0.f) continue;
    if (fabsf(d[lend - 1]) < fabsf(d[l - 1])) { lend = lsv; l = lendsv; }
    if (lend > l) {
      // ---- QL ----
      while (true) {
        int m2;
        {
          int i;
          for (i = l; i <= lend - 1; i++) {
            float tst = fabsf(e[i - 1]); tst = tst * tst;
            if (tst <= (eps2 * fabsf(d[i - 1])) * fabsf(d[i]) + safmin) break;
          }
          m2 = i;
        }
        if (m2 < lend) e[m2 - 1] = 0.f;
        float p = d[l - 1];
        if (m2 == l) { d[l - 1] = p; l++; if (l <= lend) continue; else break; }
        if (m2 == l + 1) {
          float rt1, rt2, c_, s_;
          slaev2f(d[l - 1], e[l - 1], d[l], &rt1, &rt2, &c_, &s_);
          for (int i = 0; i < n; i++) {
            float t1 = zb[l * ldz + i];
            float t0 = zb[(l - 1) * ldz + i];
            zb[l * ldz + i] = c_ * t1 - s_ * t0;
            zb[(l - 1) * ldz + i] = s_ * t1 + c_ * t0;
          }
          d[l - 1] = rt1; d[l] = rt2; e[l - 1] = 0.f;
          l += 2; if (l <= lend) continue; else break;
        }
        if (jtot == nmaxit) break;
        jtot++;
        float g = (d[l] - p) / (2.f * e[l - 1]);
        float r = slapy2f(g, 1.f);
        g = d[m2 - 1] - p + e[l - 1] / (g + copysignf(r, g));
        float s_ = 1.f, c_ = 1.f; p = 0.f;
        for (int i = m2 - 1; i >= l; i--) {
          float f = s_ * e[i - 1], b2 = c_ * e[i - 1];
          float cc, ss, rr;
          slartgf(g, f, &cc, &ss, &rr);
          c_ = cc; s_ = ss;
          if (i != m2 - 1) e[i] = rr;
          g = d[i] - p;
          rr = (d[i - 1] - g) * s_ + 2.f * c_ * b2;
          p = s_ * rr;
          d[i] = g + p;
          g = c_ * rr - b2;
          cw[i - l] = c_; sw[i - l] = -s_;
        }
        int mm2 = m2 - l + 1;
        for (int jj = mm2 - 2; jj >= 0; jj--) {
          float ct_ = cw[jj], st_ = sw[jj];
          int colj = l - 1 + jj;
          for (int i = 0; i < n; i++) {
            float t1 = zb[(colj + 1) * ldz + i];
            float t0 = zb[colj * ldz + i];
            zb[(colj + 1) * ldz + i] = ct_ * t1 - st_ * t0;
            zb[colj * ldz + i] = st_ * t1 + ct_ * t0;
          }
        }
        d[l - 1] -= p; e[l - 1] = g;
      }
    } else {
      // ---- QR ----
      while (true) {
        int m2;
        {
          int i;
          for (i = l; i >= lend + 1; i--) {
            float tst = fabsf(e[i - 2]); tst = tst * tst;
            if (tst <= (eps2 * fabsf(d[i - 1])) * fabsf(d[i - 2]) + safmin) break;
          }
          m2 = i;
        }
        if (m2 > lend) e[m2 - 2] = 0.f;
        float p = d[l - 1];
        if (m2 == l) { d[l - 1] = p; l--; if (l >= lend) continue; else break; }
        if (m2 == l - 1) {
          float rt1, rt2, c_, s_;
          slaev2f(d[l - 2], e[l - 2], d[l - 1], &rt1, &rt2, &c_, &s_);
          for (int i = 0; i < n; i++) {
            float t1 = zb[(l - 1) * ldz + i];
            float t0 = zb[(l - 2) * ldz + i];
            zb[(l - 1) * ldz + i] = c_ * t1 - s_ * t0;
            zb[(l - 2) * ldz + i] = s_ * t1 + c_ * t0;
          }
          d[l - 2] = rt1; d[l - 1] = rt2; e[l - 2] = 0.f;
          l -= 2; if (l >= lend) continue; else break;
        }
        if (jtot == nmaxit) break;
        jtot++;
        float g = (d[l - 2] - p) / (2.f * e[l - 2]);
        float r = slapy2f(g, 1.f);
        g = d[m2 - 1] - p + e[l - 2] / (g + copysignf(r, g));
        float s_ = 1.f, c_ = 1.f; p = 0.f;
        for (int i = m2; i <= l - 1; i++) {
          float f = s_ * e[i - 1], b2 = c_ * e[i - 1];
          float cc, ss, rr;
          slartgf(g, f, &cc, &ss, &rr);
          c_ = cc; s_ = ss;
          if (i != m2) e[i - 2] = rr;
          g = d[i - 1] - p;
          rr = (d[i] - g) * s_ + 2.f * c_ * b2;
          p = s_ * rr;
          d[i - 1] = g + p;
          g = c_ * rr - b2;
          cw[i - m2] = c_; sw[i - m2] = s_;
        }
        int mm2 = l - m2 + 1;
        for (int jj = 0; jj <= mm2 - 2; jj++) {
          float ct_ = cw[jj], st_ = sw[jj];
          int colj = m2 - 1 + jj;
          for (int i = 0; i < n; i++) {
            float t1 = zb[(colj + 1) * ldz + i];
            float t0 = zb[colj * ldz + i];
            zb[(colj + 1) * ldz + i] = ct_ * t1 - st_ * t0;
            zb[colj * ldz + i] = st_ * t1 + ct_ * t0;
          }
        }
        d[l - 1] -= p; e[l - 2] = g;
      }
    }
  }
  for (int ii = 2; ii <= n; ii++) {
    int i = ii - 1, k = i;
    float p = d[i - 1];
    for (int j = ii; j <= n; j++) if (d[j - 1] < p) { k = j; p = d[j - 1]; }
    if (k != i) {
      d[k - 1] = d[i - 1]; d[i - 1] = p;
      for (int r = 0; r < n; r++) {
        float t5 = zb[(i - 1) * ldz + r];
        zb[(i - 1) * ldz + r] = zb[(k - 1) * ldz + r];
        zb[(k - 1) * ldz + r] = t5;
      }
    }
  }
}

// ======================= f32 D&C merge (slaed1/2/3 semantics) =======================

__device__ void laed1_f32(float* d, float* Qm, float* Q2, float* Sm,
                          float* zv, float* dl, float* wv, float* wg, float* pvf,
                          float* dvf, int* srcx, int* dsrc, int* iq,
                          int off, int n, int n1, float rho_in,
                          int tid, int* shi, float* shdf,
                          double* sdl, double* spv, int* defcnt) {
  int n2 = n - n1;
  for (int t = tid; t < n1; t += 128) zv[t] = Qm[(off + t) * 128 + off + n1 - 1];
  for (int t = tid; t < n2; t += 128) zv[n1 + t] = Qm[(off + n1 + t) * 128 + off + n1];
  __syncthreads();
  if (tid == 0) {
    float rho = rho_in;
    if (rho < 0.f) for (int t = n1; t < n; t++) zv[t] = -zv[t];
    float tsc = 1.0f / sqrtf(2.0f);
    for (int t = 0; t < n; t++) zv[t] *= tsc;
    rho = fabsf(2.0f * rho);
    {
      int i = 0, j = n1, p = 0;
      while (i < n1 && j < n) {
        if (d[off + i] <= d[off + j]) srcx[p++] = i++; else srcx[p++] = j++;
      }
      while (i < n1) srcx[p++] = i++;
      while (j < n) srcx[p++] = j++;
    }
    int imax = 0, jmax = 0;
    for (int t = 1; t < n; t++) if (fabsf(zv[t]) > fabsf(zv[imax])) imax = t;
    for (int t = 1; t < n; t++) if (fabsf(d[off + t]) > fabsf(d[off + jmax])) jmax = t;
    float tol = 8.0f * EPSF * fmaxf(fabsf(d[off + jmax]), fabsf(zv[imax]));
    int k = 0, nd = 0;
    if (rho * fabsf(zv[imax]) <= tol) {
      for (int t = 0; t < n; t++) { dsrc[nd] = srcx[t]; dvf[nd] = d[off + srcx[t]]; nd++; }
    } else {
      int pj = -1;
      for (int jj = 0; jj < n; jj++) {
        int nj = srcx[jj];
        if (rho * fabsf(zv[nj]) <= tol) {
          dsrc[nd] = nj; dvf[nd] = d[off + nj]; nd++;
        } else if (pj < 0) {
          pj = nj;
        } else {
          float s_ = zv[pj], c_ = zv[nj];
          float tau_ = slapy2f(c_, s_);
          float t3 = d[off + nj] - d[off + pj];
          c_ /= tau_; s_ = -s_ / tau_;
          if (fabsf(t3 * c_ * s_) <= tol) {
            zv[nj] = tau_; zv[pj] = 0.f;
            for (int r = 0; r < n; r++) {
              float x_ = Qm[(off + pj) * 128 + off + r];
              float y_ = Qm[(off + nj) * 128 + off + r];
              Qm[(off + pj) * 128 + off + r] = c_ * x_ + s_ * y_;
              Qm[(off + nj) * 128 + off + r] = c_ * y_ - s_ * x_;
            }
            float dp = d[off + pj], dn = d[off + nj];
            d[off + nj] = dp * s_ * s_ + dn * c_ * c_;
            d[off + pj] = dp * c_ * c_ + dn * s_ * s_;
            dsrc[nd] = pj; dvf[nd] = d[off + pj]; nd++;
            pj = nj;
          } else {
            dl[k] = d[off + pj]; wv[k] = zv[pj]; srcx[k] = pj; k++;
            pj = nj;
          }
        }
      }
      if (pj >= 0) { dl[k] = d[off + pj]; wv[k] = zv[pj]; srcx[k] = pj; k++; }
    }
    shi[132] = k; shi[133] = nd; shdf[1] = rho;
    if (nd > 0) atomicAdd(defcnt, nd);
  }
  __syncthreads();
  int k = shi[132], nd = shi[133];
  float rho = shdf[1];
  if (k > 0) {
    if (k == 1) {
      if (tid == 0) {
        zv[0] = dl[0] + rho * (wv[0] * wv[0]);
        for (int r = 0; r < n; r++) Q2[r] = Qm[(off + srcx[0]) * 128 + off + r];
      }
      __syncthreads();
    } else {
      for (int t = tid; t < k; t += 128) {
        sdl[t] = (double)dl[t];
        spv[t] = (double)rho * (double)wv[t] * (double)wv[t];
      }
      __syncthreads();
      // secular roots in f64, shifted frame: lambda_j = dl_j + eta
      if (tid < k) {
        int j = tid;
        double lo = 0.0, hi;
        if (j == k - 1) {
          double sw2 = 0.0;
          for (int t = 0; t < k; t++) sw2 += spv[t];
          hi = sw2;
          for (int g2 = 0; g2 < 8; g2++) {
            double f = 1.0;
            for (int t = 0; t < k; t++) f += spv[t] / ((sdl[t] - sdl[j]) - hi);
            if (f >= 0.0) break;
            hi *= 2.0;
          }
        } else hi = sdl[j + 1] - sdl[j];
        double gap = hi;
        for (int it = 0; it < 110; it++) {
          double mid = 0.5 * (lo + hi);
          if (!(mid > lo && mid < hi)) break;
          double f = 1.0;
          for (int t = 0; t < k; t++) f += spv[t] / ((sdl[t] - sdl[j]) - mid);
          if (f < 0.0) lo = mid; else hi = mid;
        }
        double eta = 0.5 * (lo + hi);
        if (eta <= 0.0) eta = gap * 1e-30;
        if (j < k - 1 && eta >= gap) eta = gap * (1.0 - 1e-15);
        d[off + j] = (float)(sdl[j] + eta);
        for (int t = 0; t < k; t++)
          Sm[j * 128 + t] = (float)((sdl[t] - sdl[j]) - eta);
      }
      __syncthreads();
      // Gu-Eisenstat reweighting (f32, as slaed3)
      if (tid < k) {
        int i = tid;
        float acc = Sm[i * 128 + i];
        for (int j = 0; j < k; j++) {
          if (j == i) continue;
          acc *= Sm[j * 128 + i] / (dl[i] - dl[j]);
        }
        wg[i] = copysignf(sqrtf(fmaxf(-acc, 0.f)), wv[i]);
      }
      __syncthreads();
      // secular vectors, positive normalization, direct gather
      if (tid < k) {
        int j = tid;
        float nrm2 = 0.f;
        for (int i = 0; i < k; i++) {
          float u = wg[i] / Sm[j * 128 + i];
          Sm[j * 128 + i] = u;
          nrm2 += u * u;
        }
        float nrm = sqrtf(nrm2);
        for (int i = 0; i < k; i++) Sm[j * 128 + i] /= nrm;
        for (int r = 0; r < n; r++) {
          float acc = 0.f;
          for (int i = 0; i < k; i++)
            acc += Qm[(off + srcx[i]) * 128 + off + r] * Sm[j * 128 + i];
          Q2[j * 128 + r] = acc;
        }
      }
      __syncthreads();
      if (k == 1) {}  // unreachable
      if (tid < k && k == 1) {}
      // store k==... handled; store lambda for k>1 done above via d
      if (tid < k) zv[tid] = d[off + tid];
      __syncthreads();
    }
  }
  for (int t2 = tid; t2 < nd; t2 += 128)
    for (int r = 0; r < n; r++) Q2[(k + t2) * 128 + r] = Qm[(off + dsrc[t2]) * 128 + off + r];
  for (int j = tid; j < n; j += 128) pvf[j] = (j < k) ? zv[j] : dvf[j - k];
  __syncthreads();
  // ascending physical sort (stable: secular wins ties, encounter order after)
  if (tid == 0) {
    for (int i = 0; i < n; i++) iq[i] = i;
    for (int i = 0; i < n - 1; i++) {
      int kb = i;
      for (int j = i + 1; j < n; j++) if (pvf[iq[j]] < pvf[iq[kb]]) kb = j;
      if (kb != i) { int tt = iq[i]; iq[i] = iq[kb]; iq[kb] = tt; }
    }
  }
  __syncthreads();
  for (int j = tid; j < n; j += 128) {
    int s2 = iq[j];
    d[off + j] = pvf[s2];
    for (int r = 0; r < n; r++) Qm[(off + j) * 128 + off + r] = Q2[s2 * 128 + r];
  }
  __syncthreads();
}

__device__ void laed0_f32(float* d, float* e, float* Qm, float* Q2, float* Sm,
                          float* zv, float* dl, float* wv, float* wg, float* pvf,
                          float* dvf, int* srcx, int* dsrc, int* iq,
                          int goff, int m, int tid, int* shi, float* shdf,
                          double* sdl, double* spv, int* defcnt) {
  int iwp[64];
  iwp[0] = m; int subpbs = 1;
  while (iwp[subpbs - 1] > SMLSIZ) {
    for (int j = subpbs - 1; j >= 0; j--) { iwp[2 * j + 1] = (iwp[j] + 1) / 2; iwp[2 * j] = iwp[j] / 2; }
    subpbs *= 2;
  }
  for (int j = 1; j < subpbs; j++) iwp[j] += iwp[j - 1];
  if (tid == 0) {
    for (int i = 0; i < subpbs - 1; i++) {
      int bnd = goff + iwp[i];
      d[bnd - 1] -= fabsf(e[bnd - 1]);
      d[bnd] -= fabsf(e[bnd - 1]);
    }
  }
  __syncthreads();
  // leaves: faithful serial ssteqr per sub-block (signs now output-visible!)
  if (tid < subpbs) {
    int boff = goff + (tid == 0 ? 0 : iwp[tid - 1]);
    int bm = iwp[tid] - (tid == 0 ? 0 : iwp[tid - 1]);
    steqr_f32(d + boff, e + boff, bm, Qm + boff * 128 + boff, 128);
  }
  __syncthreads();
  int cur = subpbs;
  while (cur > 1) {
    for (int p = 0; p < cur; p += 2) {
      int off2 = goff + (p == 0 ? 0 : iwp[p - 1]);
      int msz = iwp[p + 1] - (p == 0 ? 0 : iwp[p - 1]);
      int msd2 = (p == 0) ? iwp[0] : (msz / 2);
      float rho = e[off2 + msd2 - 1];
      laed1_f32(d, Qm, Q2, Sm, zv, dl, wv, wg, pvf, dvf, srcx, dsrc, iq,
                off2, msz, msd2, rho, tid, shi, shdf, sdl, spv, defcnt);
    }
    for (int t = 0; 2 * t + 1 < cur; t++) iwp[t] = iwp[2 * t + 1];
    cur /= 2;
  }
}

// ======================= eig kernel: ssyevd emulation per batch =======================

__global__ __launch_bounds__(128) void eig_f32_kernel(float* covA, float* Qw, float* Q2w,
                                                      float* Sw, float* vecs, int* iwsp,
                                                      float* Vw, int* defcnt) {
  int b = blockIdx.x, tid = threadIdx.x;
  float* A   = covA + (size_t)b * 16384;
  float* Qm  = Qw + (size_t)b * 16384;
  float* Q2  = Q2w + (size_t)b * 16640;
  float* Sm  = Sw + (size_t)b * 16384;
  float* d    = vecs + b * 128;
  float* e    = vecs + 2048 + b * 128;
  float* tauv = vecs + 4096 + b * 128;
  float* zv   = vecs + 6144 + b * 128;
  float* dl   = vecs + 8192 + b * 128;
  float* wv   = vecs + 10240 + b * 128;
  float* wg   = vecs + 12288 + b * 128;
  float* pvf  = vecs + 14336 + b * 128;
  float* dvf  = vecs + 16384 + b * 128;
  int* iq   = iwsp + b * 128;
  int* srcx = iwsp + 2048 + b * 128;
  int* dsrc = iwsp + 4096 + b * 128;
  __shared__ float redf[128];
  __shared__ float shdf[8];
  __shared__ int shi[280];
  __shared__ double sdl[128];
  __shared__ double spv[128];

  // ---------- Phase 1: ssytd2 (UPLO='L') ----------
  for (int i1 = 1; i1 <= NC - 1; i1++) {
    int ii = i1 - 1;
    int mlen = NC - i1;
    float alpha = A[ii * 128 + ii + 1];
    float ps = 0.f;
    for (int t = tid; t < mlen - 1; t += 128) {
      float v = A[ii * 128 + ii + 2 + t];
      ps += v * v;
    }
    redf[tid] = ps;
    __syncthreads();
    for (int sft = 64; sft > 0; sft >>= 1) {
      if (tid < sft) redf[tid] += redf[tid + sft];
      __syncthreads();
    }
    float xnorm = sqrtf(redf[0]);
    __syncthreads();
    float taui, ei;
    if (xnorm == 0.f) { taui = 0.f; ei = alpha; }
    else {
      float beta = -copysignf(slapy2f(alpha, xnorm), alpha);
      taui = (beta - alpha) / beta;
      float scl = 1.f / (alpha - beta);
      ei = beta;
      for (int t = tid; t < mlen - 1; t += 128) A[ii * 128 + ii + 2 + t] *= scl;
    }
    if (tid == 0) { e[ii] = ei; tauv[ii] = taui; A[ii * 128 + ii + 1] = 1.f; }
    __syncthreads();
    if (taui != 0.f) {
      for (int r = tid; r < mlen; r += 128) {
        float acc = 0.f;
        int row = ii + 1 + r;
        for (int s = 0; s < mlen; s++) acc += A[(ii + 1 + s) * 128 + row] * A[ii * 128 + ii + 1 + s];
        pvf[r] = taui * acc;
      }
      __syncthreads();
      float pd = 0.f;
      for (int t = tid; t < mlen; t += 128) pd += pvf[t] * A[ii * 128 + ii + 1 + t];
      redf[tid] = pd;
      __syncthreads();
      for (int sft = 64; sft > 0; sft >>= 1) {
        if (tid < sft) redf[tid] += redf[tid + sft];
        __syncthreads();
      }
      float alpha2 = -0.5f * taui * redf[0];
      __syncthreads();
      for (int t = tid; t < mlen; t += 128) pvf[t] += alpha2 * A[ii * 128 + ii + 1 + t];
      __syncthreads();
      for (int idx = tid; idx < mlen * mlen; idx += 128) {
        int r = idx % mlen, c2 = idx / mlen;
        A[(ii + 1 + c2) * 128 + (ii + 1 + r)] -=
            A[ii * 128 + ii + 1 + r] * pvf[c2] + pvf[r] * A[ii * 128 + ii + 1 + c2];
      }
      __syncthreads();
    }
    if (tid == 0) A[ii * 128 + ii + 1] = ei;
    __syncthreads();
  }
  for (int t = tid; t < NC; t += 128) d[t] = A[t * 128 + t];
  __syncthreads();

  // ---------- Phase 2: sstedc('I') ----------
  for (int idx = tid; idx < 16384; idx += 128) Qm[idx] = (idx % 129 == 0) ? 1.f : 0.f;
  __syncthreads();
  if (tid == 0) {
    int ns = 0, start = 0;
    while (start < NC) {
      int fin = start;
      while (fin < NC - 1) {
        float tiny = EPSF * sqrtf(fabsf(d[fin])) * sqrtf(fabsf(d[fin + 1]));
        if (fabsf(e[fin]) > tiny) fin++;
        else break;
      }
      shi[2 + 2 * ns] = start; shi[3 + 2 * ns] = fin - start + 1; ns++;
      start = fin + 1;
    }
    shi[0] = ns;
  }
  __syncthreads();
  int nsplit = shi[0];
  for (int sb = 0; sb < nsplit; sb++) {
    int goff = shi[2 + 2 * sb], m = shi[3 + 2 * sb];
    if (m == 1) continue;
    if (m <= SMLSIZ) {
      if (tid == 0) steqr_f32(d + goff, e + goff, m, Qm + goff * 128 + goff, 128);
      __syncthreads();
    } else {
      if (tid == 0) {
        float mx = 0.f;
        for (int i = 0; i < m; i++) mx = fmaxf(mx, fabsf(d[goff + i]));
        for (int i = 0; i < m - 1; i++) mx = fmaxf(mx, fabsf(e[goff + i]));
        shdf[0] = mx;
      }
      __syncthreads();
      float onrm = shdf[0];
      if (onrm != 0.f) {
        float mul = 1.f / onrm;
        for (int t = tid; t < m; t += 128) d[goff + t] *= mul;
        for (int t = tid; t < m - 1; t += 128) e[goff + t] *= mul;
        __syncthreads();
        laed0_f32(d, e, Qm, Q2, Sm, zv, dl, wv, wg, pvf, dvf, srcx, dsrc, iq,
                  goff, m, tid, shi, shdf, sdl, spv, defcnt);
        for (int t = tid; t < m; t += 128) d[goff + t] *= onrm;
        __syncthreads();
      }
    }
  }
  if (tid == 0) {
    for (int i = 0; i < NC; i++) shi[140 + i] = i;
    for (int ii2 = 2; ii2 <= NC; ii2++) {
      int i = ii2 - 1, kk2 = i;
      float p = d[i - 1];
      for (int j = ii2; j <= NC; j++) if (d[j - 1] < p) { kk2 = j; p = d[j - 1]; }
      if (kk2 != i) {
        d[kk2 - 1] = d[i - 1]; d[i - 1] = p;
        int tmp = shi[140 + i - 1]; shi[140 + i - 1] = shi[140 + kk2 - 1]; shi[140 + kk2 - 1] = tmp;
      }
    }
  }
  __syncthreads();
  {
    int j = tid;
    int src = shi[140 + j];
    for (int r = 0; r < NC; r++) Q2[j * 128 + r] = Qm[src * 128 + r];
  }
  __syncthreads();
  {
    int j = tid;
    for (int r = 0; r < NC; r++) Qm[j * 128 + r] = Q2[j * 128 + r];
  }
  __syncthreads();

  // ---------- Phase 3: sormtr('L','L','N') ----------
  for (int j1 = NC - 1; j1 >= 1; j1--) {
    int jj = j1 - 1;
    float tj = tauv[jj];
    if (tj != 0.f) {
      int col = tid;
      float s = Qm[col * 128 + jj + 1];
      for (int r = jj + 2; r < NC; r++) s += A[jj * 128 + r] * Qm[col * 128 + r];
      s *= tj;
      Qm[col * 128 + jj + 1] -= s;
      for (int r = jj + 2; r < NC; r++) Qm[col * 128 + r] -= s * A[jj * 128 + r];
    }
  }
  __syncthreads();

  // ---------- Phase 4: extract top-64 descending ----------
  for (int idx = tid; idx < NC * KTOP; idx += 128) {
    int c2 = idx / KTOP, kk = idx % KTOP;
    Vw[(size_t)b * (NC * KTOP) + idx] = Qm[(127 - kk) * 128 + c2];
  }
}

// ======================= diagnostics =======================

__global__ void zeroi_kernel(int* p) { p[0] = 0; p[1] = 0; }

__global__ __launch_bounds__(128) void diag_kernel(const float* __restrict__ covB,
                                                   const float* __restrict__ Qw,
                                                   const float* __restrict__ vecs,
                                                   const float* __restrict__ Vw, int* dcode) {
  int b = blockIdx.x, tid = threadIdx.x;
  const float* C = covB + (size_t)b * 16384;
  const float* Qm = Qw + (size_t)b * 16384;
  const float* d = vecs + b * 128;
  int flags = 0;
  double rmax = 0.0;
  for (int k = 64; k < 128; k++) {
    double lam = (double)d[k];
    double acc = 0.0;
    for (int j = 0; j < 128; j++) acc += (double)C[j * 128 + tid] * (double)Qm[k * 128 + j];
    acc -= lam * (double)Qm[k * 128 + tid];
    rmax = fmax(rmax, fabs(acc));
  }
  if (rmax > 1e-3) flags |= 1;
  double omax = 0.0;
  for (int p = tid; p < 64 * 64; p += 128) {
    int i = 64 + p / 64, j = 64 + p % 64;
    if (j < i) continue;
    double s = 0.0;
    for (int r = 0; r < 128; r++) s += (double)Qm[i * 128 + r] * (double)Qm[j * 128 + r];
    if (i == j) s -= 1.0;
    omax = fmax(omax, fabs(s));
  }
  if (omax > 1e-3) flags |= 2;
  if (tid < 127 && d[tid + 1] < d[tid] - 1e-5f) flags |= 4;
  for (int idx = tid; idx < 8192; idx += 128) {
    int c2 = idx / 64, kk = idx % 64;
    if (Vw[(size_t)b * 8192 + idx] != Qm[(127 - kk) * 128 + c2]) flags |= 8;
  }
  if (tid == 0) {
    for (int k = 64; k < 128; k++) if (!(d[k] > 0.2f && d[k] < 5.0f)) flags |= 16;
    float s = 0.f;
    for (int c = 0; c < 128; c++) { float v = Vw[(size_t)b * 8192 + c * 64]; s += v * v; }
    if (fabsf(s - 1.f) > 1e-2f) flags |= 32;
  }
  if (flags) atomicOr(dcode, flags);
}

__global__ void emit_kernel(const int* dcode, float* out) {
  int f = dcode[0];
  if (f) {
    int code = 1000;
    if (f & 1) code += 400;
    if (f & 2) code += 200;
    if (f & 4) code += 100;
    if (f & 8) code += 40;
    if (f & 16) code += 20;
    if (f & 32) code += 10;
    int nd = dcode[1]; if (nd > 9) nd = 9;
    code += nd;
    out[0] = (float)code;
  }
}

// ======================= numpy-f32-mirror mean / cov =======================

__global__ __launch_bounds__(128) void mean_np_kernel(const float* __restrict__ x,
                                                      float* __restrict__ mean32) {
  int b = blockIdx.x, c = threadIdx.x;
  const float* xb = x + (size_t)b * 2097152;
  float s = 0.0f;
  for (int n = 0; n < 16384; n++) s = __fadd_rn(s, xb[n * 128 + c]);
  mean32[b * 128 + c] = s / 16384.0f;
}

__global__ __launch_bounds__(256) void covnp_kernel(const float* __restrict__ x,
                                                    const float* __restrict__ mean32,
                                                    float* __restrict__ S) {
  int b = blockIdx.x;
  int ti = (blockIdx.y & 3) * 32, tj = (blockIdx.y >> 2) * 32;
  __shared__ float XI[32 * 64], XJ[32 * 64];
  int tid = threadIdx.x;
  int ci = 2 * (tid & 15), dj = 2 * (tid >> 4);
  float a00 = 0.f, a01 = 0.f, a10 = 0.f, a11 = 0.f;
  const float* xb = x + (size_t)b * 2097152;
  const float* mb = mean32 + b * 128;
  for (int n0 = 0; n0 < 16384; n0 += 64) {
    __syncthreads();
    for (int l = tid; l < 2048; l += 256) {
      int n = l >> 5, cc = l & 31;
      XI[cc * 64 + n] = __fsub_rn(xb[(n0 + n) * 128 + ti + cc], mb[ti + cc]);
      XJ[cc * 64 + n] = __fsub_rn(xb[(n0 + n) * 128 + tj + cc], mb[tj + cc]);
    }
    __syncthreads();
    const float* pi0 = &XI[ci * 64];
    const float* pi1 = pi0 + 64;
    const float* pj0 = &XJ[dj * 64];
    const float* pj1 = pj0 + 64;
    for (int n = 0; n < 64; n++) {
      float ai0 = pi0[n], ai1 = pi1[n], bj0 = pj0[n], bj1 = pj1[n];
      a00 = __fadd_rn(a00, __fmul_rn(ai0, bj0));
      a01 = __fadd_rn(a01, __fmul_rn(ai0, bj1));
      a10 = __fadd_rn(a10, __fmul_rn(ai1, bj0));
      a11 = __fadd_rn(a11, __fmul_rn(ai1, bj1));
    }
  }
  float* Sb = S + (size_t)b * 16384;
  int C = ti + ci, D = tj + dj;
  Sb[C * 128 + D] = a00;
  Sb[C * 128 + D + 1] = a01;
  Sb[(C + 1) * 128 + D] = a10;
  Sb[(C + 1) * 128 + D + 1] = a11;
}

__global__ void covfin_kernel(float* __restrict__ A, float* __restrict__ B) {
  int i = blockIdx.x * 256 + threadIdx.x;
  if (i < 262144) {
    float v = A[i] / 16383.0f;
    A[i] = v;
    B[i] = v;
  }
}

// ======================= projection =======================

__global__ __launch_bounds__(256) void proj_kernel(const float* __restrict__ x, const float* __restrict__ V,
                                                   const float* __restrict__ mean32, float* __restrict__ out) {
  __shared__ float Vs[128 * 64];
  __shared__ float Xs[64 * 128];
  __shared__ float ms[128];
  int b = blockIdx.x, t = blockIdx.y, tid = threadIdx.x;
  const float* xb = x + (size_t)b * 2097152 + (size_t)t * 64 * 128;
  const float* vb = V + (size_t)b * 8192;
  if (tid < 128) ms[tid] = mean32[b * 128 + tid];
  __syncthreads();
  for (int i = tid; i < 2048; i += 256) ((float4*)Vs)[i] = ((const float4*)vb)[i];
  for (int i = tid; i < 2048; i += 256) {
    float4 xv = ((const float4*)xb)[i];
    int cv = (i & 31) * 4;
    xv.x -= ms[cv]; xv.y -= ms[cv + 1]; xv.z -= ms[cv + 2]; xv.w -= ms[cv + 3];
    ((float4*)Xs)[i] = xv;
  }
  __syncthreads();
  int kk = tid & 63, w = tid >> 6;
  float acc[16];
#pragma unroll
  for (int r = 0; r < 16; r++) acc[r] = 0.f;
  for (int c4 = 0; c4 < 32; c4++) {
    float v0 = Vs[(c4 * 4 + 0) * 64 + kk];
    float v1 = Vs[(c4 * 4 + 1) * 64 + kk];
    float v2 = Vs[(c4 * 4 + 2) * 64 + kk];
    float v3 = Vs[(c4 * 4 + 3) * 64 + kk];
#pragma unroll
    for (int r = 0; r < 16; r++) {
      const float4 xv = ((const float4*)Xs)[(w * 16 + r) * 32 + c4];
      acc[r] += xv.x * v0 + xv.y * v1 + xv.z * v2 + xv.w * v3;
    }
  }
  float* ob = out + (size_t)b * 1048576 + (size_t)t * 4096;
#pragma unroll
  for (int r = 0; r < 16; r++) ob[(w * 16 + r) * 64 + kk] = acc[r];
}

// ======================= launch =======================

extern "C" void kernel_launch(void* const* d_in, const int* in_sizes, int n_in,
                              void* d_out, int out_size, void* d_ws, size_t ws_size,
                              hipStream_t stream) {
  (void)in_sizes; (void)n_in; (void)out_size; (void)ws_size;
  const float* x = (const float*)d_in[0];
  float* out = (float*)d_out;
  float* T = out + TBASEF;
  float* Af   = T + F_A;
  float* Bf   = T + F_B;
  float* Qf   = T + F_Q;
  float* Q2f  = T + F_Q2;
  float* Smf  = T + F_SM;
  float* vecsf = T + F_VECS;
  int* iwsp = (int*)(T + F_IWSP);
  float* Vw = (float*)d_ws;
  float* mean32 = Vw + 131072;
  int* dcode = (int*)(mean32 + 2048);

  zeroi_kernel<<<dim3(1), dim3(1), 0, stream>>>(dcode);
  mean_np_kernel<<<dim3(16), dim3(128), 0, stream>>>(x, mean32);
  covnp_kernel<<<dim3(16, 16), dim3(256), 0, stream>>>(x, mean32, Af);
  covfin_kernel<<<dim3(1024), dim3(256), 0, stream>>>(Af, Bf);
  eig_f32_kernel<<<dim3(16), dim3(128), 0, stream>>>(Af, Qf, Q2f, Smf, vecsf, iwsp, Vw, dcode + 1);
  diag_kernel<<<dim3(16), dim3(128), 0, stream>>>(Bf, Qf, vecsf, Vw, dcode);
  proj_kernel<<<dim3(16, 256), dim3(256), 0, stream>>>(x, Vw, mean32, out);
  emit_kernel<<<dim3(1), dim3(1), 0, stream>>>(dcode, out);
}